// Round 8
// baseline (139.395 us; speedup 1.0000x reference)
//
#include <hip/hip_runtime.h>
#include <hip/hip_bf16.h>
#include <stdint.h>
#include <math.h>

typedef __bf16 bf16_t;
typedef bf16_t bf16x8 __attribute__((ext_vector_type(8)));
typedef float f32x4 __attribute__((ext_vector_type(4)));

#define B_DIM 8
#define N_DIM 2048
#define D_DIM 512
// (1/sqrt(512)) * log2(e): folded into Q so softmax uses exp2 directly
#define QK_SCALE_L2E 0.063758716f
#define M_SHIFT2 5.7707801635558536f   /* 4 * log2(e); P = exp2(S' - M) = e^(S-4) */

// attn LDS layout (bytes): K dbuf x2, V dbuf x2, P dbuf x2  (144 KB)
#define KOFF 0            // 2 x 32768 ([32 k][512 d] bf16, 16B-slot ^ (row&7))
#define VOFF 65536        // 2 x 32768 ([512 d][32 k] bf16, k pre-permuted, slot ^ ((d>>1)&3))
#define POFF 131072       // 2 x 8192  ([128 q][32 k] bf16, slot ^ ((q>>1)&3), k-order = V's)
#define SMEM_ATTN 147456

__device__ __forceinline__ bf16_t f2bf(float f) {
    uint32_t u = __builtin_bit_cast(uint32_t, f);
    u += 0x7FFFu + ((u >> 16) & 1u);
    uint16_t h = (uint16_t)(u >> 16);
    return __builtin_bit_cast(bf16_t, h);
}

__device__ __forceinline__ float fexp2(float x) {
    float r;
    asm("v_exp_f32 %0, %1" : "=v"(r) : "v"(x));
    return r;
}

// ---------------- Kernel 1: fused LayerNorm + Q/K prep + permuted V^T ----------------
__global__ __launch_bounds__(512) void prep_fused(
    const float* __restrict__ x, const float* __restrict__ w, const float* __restrict__ bia,
    const float* __restrict__ qd, const float* __restrict__ kd, const float* __restrict__ vd,
    bf16_t* __restrict__ xnb, float* __restrict__ xnf,
    bf16_t* __restrict__ qb, bf16_t* __restrict__ kb, bf16_t* __restrict__ vT)
{
    extern __shared__ char pmem[];
    bf16_t (*vt)[512] = (bf16_t(*)[512])pmem;   // [64 n][512 d], 64 KB

    const int bid = blockIdx.x;
    const int b  = bid >> 5;
    const int n0 = (bid & 31) * 64;
    const int tid  = threadIdx.x;
    const int wid  = tid >> 6;
    const int lane = tid & 63;
    const int d    = lane * 8;

    float wv[8], bv[8], qv[8], kv[8], vv[8];
    {
        float4 t;
        t = *(const float4*)(w  + d);     wv[0]=t.x; wv[1]=t.y; wv[2]=t.z; wv[3]=t.w;
        t = *(const float4*)(w  + d + 4); wv[4]=t.x; wv[5]=t.y; wv[6]=t.z; wv[7]=t.w;
        t = *(const float4*)(bia+ d);     bv[0]=t.x; bv[1]=t.y; bv[2]=t.z; bv[3]=t.w;
        t = *(const float4*)(bia+ d + 4); bv[4]=t.x; bv[5]=t.y; bv[6]=t.z; bv[7]=t.w;
        t = *(const float4*)(qd + d);     qv[0]=t.x; qv[1]=t.y; qv[2]=t.z; qv[3]=t.w;
        t = *(const float4*)(qd + d + 4); qv[4]=t.x; qv[5]=t.y; qv[6]=t.z; qv[7]=t.w;
        t = *(const float4*)(kd + d);     kv[0]=t.x; kv[1]=t.y; kv[2]=t.z; kv[3]=t.w;
        t = *(const float4*)(kd + d + 4); kv[4]=t.x; kv[5]=t.y; kv[6]=t.z; kv[7]=t.w;
        t = *(const float4*)(vd + d);     vv[0]=t.x; vv[1]=t.y; vv[2]=t.z; vv[3]=t.w;
        t = *(const float4*)(vd + d + 4); vv[4]=t.x; vv[5]=t.y; vv[6]=t.z; vv[7]=t.w;
    }

    for (int r = 0; r < 8; r++) {
        int nl = wid*8 + r;
        size_t row  = (size_t)b*N_DIM + n0 + nl;
        size_t base = row*D_DIM + d;
        float xv[8];
        {
            float4 a0 = *(const float4*)(x + base);
            float4 a1 = *(const float4*)(x + base + 4);
            xv[0]=a0.x; xv[1]=a0.y; xv[2]=a0.z; xv[3]=a0.w;
            xv[4]=a1.x; xv[5]=a1.y; xv[6]=a1.z; xv[7]=a1.w;
        }
        float s = 0.f, s2 = 0.f;
        #pragma unroll
        for (int j = 0; j < 8; j++) { s += xv[j]; s2 += xv[j]*xv[j]; }
        #pragma unroll
        for (int m = 1; m < 64; m <<= 1) {
            s  += __shfl_xor(s,  m);
            s2 += __shfl_xor(s2, m);
        }
        float mu   = s  * (1.f/512.f);
        float var  = s2 * (1.f/512.f) - mu*mu;
        float rstd = rsqrtf(var + 1e-5f);

        float xo[8];
        bf16x8 qo, ko, xb, vb;
        #pragma unroll
        for (int j = 0; j < 8; j++) {
            float v = (xv[j] - mu) * rstd * wv[j] + bv[j];
            xo[j] = v;
            xb[j] = f2bf(v);
            qo[j] = f2bf(v * qv[j] * QK_SCALE_L2E);
            ko[j] = f2bf(v * kv[j]);
            vb[j] = f2bf(v * vv[j]);
        }
        if (xnb) {
            *(bf16x8*)(xnb + base) = xb;
        } else {
            float4 o0 = {xo[0],xo[1],xo[2],xo[3]};
            float4 o1 = {xo[4],xo[5],xo[6],xo[7]};
            *(float4*)(xnf + base)     = o0;
            *(float4*)(xnf + base + 4) = o1;
        }
        *(bf16x8*)(qb + base) = qo;
        *(bf16x8*)(kb + base) = ko;
        *(bf16x8*)(&vt[nl][d]) = vb;
    }
    __syncthreads();

    // vT: slot sp holds logical g = sp ^ ((d>>1)&3): k = {4g..4g+3, 16+4g..16+4g+3}
    {
        const int dd = tid;
        const int salt = (dd >> 1) & 3;
        bf16_t* vrow = vT + ((size_t)(b*D_DIM + dd))*N_DIM + n0;
        #pragma unroll
        for (int kb2 = 0; kb2 < 2; kb2++) {
            #pragma unroll
            for (int sp = 0; sp < 4; sp++) {
                int gg = sp ^ salt;
                bf16x8 o;
                #pragma unroll
                for (int e = 0; e < 4; e++) o[e]   = vt[kb2*32 + 4*gg + e][dd];
                #pragma unroll
                for (int e = 0; e < 4; e++) o[4+e] = vt[kb2*32 + 16 + 4*gg + e][dd];
                *(bf16x8*)(vrow + kb2*32 + sp*8) = o;
            }
        }
    }
}

// ---------------- Kernel 2: flash attention (hybrid: q-slice QK, d-slice PV) ----------------
// grid 256: XCD-grouped (batch,split) x 16 qtiles. 512 thr = 8 waves.
// Iter t: stageV(t) -> vmcnt(4) -> stageK(t+1) -> QK(t) || PV(t-1) || softmax(t)->P(t)
//         -> lgkm(0) + barrier.  K/V/P all double-buffered; vmcnt never 0 in loop.
// Wave w: QK+softmax for q-rows [w*16,w*16+16) (lane-local, swapped MFMA);
//         PV owns d-cols [w*64,w*64+64) x all 128 q (reads P of all waves from LDS).
__global__ __launch_bounds__(512, 2) void attn8(
    const bf16_t* __restrict__ qb, const bf16_t* __restrict__ kb,
    const bf16_t* __restrict__ vT, bf16_t* __restrict__ opart, float* __restrict__ stats)
{
    extern __shared__ char smem[];

    const int bid = blockIdx.x;
    const int xcd = bid & 7, jj = bid >> 3;
    const int grp = xcd + 8*(jj >> 4);   // (b,s) group -> one XCD
    const int qt  = jj & 15;
    const int b   = grp >> 1;
    const int s   = grp & 1;
    const int q0  = qt * 128;
    const int n0base = s * 1024;

    const int tid  = threadIdx.x;
    const int wid  = tid >> 6;
    const int lane = tid & 63;
    const int g    = lane >> 4;
    const int li   = lane & 15;

    const bf16_t* kb_b = kb + (size_t)b * N_DIM * D_DIM;
    const bf16_t* vT_b = vT + (size_t)b * D_DIM * N_DIM;

    // Q fragments (loop-invariant): rows q0 + wid*16 + li over all 512 d
    bf16x8 qf[16];
    {
        const bf16_t* qp = qb + ((size_t)(b*N_DIM + q0 + wid*16 + li)) * D_DIM + g*8;
        #pragma unroll
        for (int ks = 0; ks < 16; ks++)
            qf[ks] = *(const bf16x8*)(qp + ks*32);
    }

    // acc[m*4+j]: q-frag m (rows m*16..), d-frag j (cols wid*64+j*16..)
    f32x4 acc[32];
    const f32x4 zf = {0.f, 0.f, 0.f, 0.f};
    #pragma unroll
    for (int j = 0; j < 32; j++) acc[j] = zf;

    float l_r = 0.f;

    const int Lk = (lane ^ wid) * 8;
    auto stageK = [&](int buf, int t) {
        const int kstart = n0base + t*32;
        char* kdst = smem + KOFF + buf*32768;
        #pragma unroll
        for (int v = 0; v < 4; v++) {
            int row = v*8 + wid;
            const bf16_t* src = kb_b + (size_t)(kstart + row)*D_DIM + Lk;
            __builtin_amdgcn_global_load_lds((const void*)src, (void*)(kdst + row*1024), 16, 0, 0);
        }
    };
    auto stageV = [&](int buf, int t) {
        const int kstart = n0base + t*32;
        char* vdst = smem + VOFF + buf*32768 + wid*4096;
        const int drow = wid*64 + (lane >> 2);
        const bf16_t* src0 = vT_b + (size_t)drow*N_DIM + kstart + (lane & 3)*8;
        #pragma unroll
        for (int v = 0; v < 4; v++) {
            __builtin_amdgcn_global_load_lds((const void*)(src0 + (size_t)(v*16)*N_DIM),
                                             (void*)(vdst + v*1024), 16, 0, 0);
        }
    };

    // prologue: stage K(0), confirm, barrier
    stageK(0, 0);
    asm volatile("s_waitcnt vmcnt(0)" ::: "memory");
    __builtin_amdgcn_s_barrier();

    const int sw  = li & 7;           // K-read salt
    const int ps  = (li >> 1) & 3;    // P/V slot salt
    const int psw = (g ^ ps) << 4;

    #pragma unroll 1
    for (int t = 0; t < 32; ++t) {
        const int cb = t & 1;         // current K/P buffer; V(t) staged here
        const int pb = cb ^ 1;        // prev V/P buffer (tile t-1)

        // [1] stage V(t) -> slot cb (old V(t-2) readers retired before last barrier)
        stageV(cb, t);
        __builtin_amdgcn_sched_barrier(0);
        // [2] confirm V(t-1) + K(t); V(t) stays in flight
        asm volatile("s_waitcnt vmcnt(4)" ::: "memory");
        __builtin_amdgcn_sched_barrier(0);
        // [3] stage K(t+1) -> slot pb (old K(t-1) readers retired before last barrier)
        if (t < 31) stageK(pb, t + 1);
        __builtin_amdgcn_sched_barrier(0);

        // [4a] QK(t): S^T[32 k][16 q]; lane: q=li, k = 4g+r (s0) / 16+4g+r (s1)
        const char* kr0 = smem + KOFF + cb*32768 + li*1024;
        const char* kr1 = kr0 + 16*1024;
        f32x4 s0 = zf, s1 = zf;
        __builtin_amdgcn_s_setprio(1);
        #pragma unroll
        for (int ks = 0; ks < 16; ks++) {
            int phys = (((ks << 2) + g) ^ sw) << 4;
            bf16x8 k0 = *(const bf16x8*)(kr0 + phys);
            bf16x8 k1 = *(const bf16x8*)(kr1 + phys);
            s0 = __builtin_amdgcn_mfma_f32_16x16x32_bf16(k0, qf[ks], s0, 0, 0, 0);
            s1 = __builtin_amdgcn_mfma_f32_16x16x32_bf16(k1, qf[ks], s1, 0, 0, 0);
        }
        __builtin_amdgcn_s_setprio(0);

        // [4b] PV(t-1): O[128 q][wid*64..+64] += P(t-1) * V(t-1); both from LDS slot pb
        if (t > 0) {
            const char* Pp = smem + POFF + pb*8192;
            const char* Vp = smem + VOFF + pb*32768 + (size_t)(wid*64 + li)*64 + psw;
            bf16x8 bv[4];
            #pragma unroll
            for (int j = 0; j < 4; j++)
                bv[j] = *(const bf16x8*)(Vp + j*1024);
            __builtin_amdgcn_s_setprio(1);
            #pragma unroll
            for (int m = 0; m < 8; m++) {
                bf16x8 pa = *(const bf16x8*)(Pp + (m*16 + li)*64 + psw);
                #pragma unroll
                for (int j = 0; j < 4; j++)
                    acc[m*4+j] = __builtin_amdgcn_mfma_f32_16x16x32_bf16(pa, bv[j], acc[m*4+j], 0, 0, 0);
            }
            __builtin_amdgcn_s_setprio(0);
        }

        // [4c] softmax(t): P = exp2(S' - 4*log2e); pack lane's 8 values -> one b128 write
        {
            bf16x8 pw;
            float la = 0.f, lb2 = 0.f;
            #pragma unroll
            for (int r = 0; r < 4; r++) {
                float e0 = fexp2(s0[r] - M_SHIFT2);
                float e1 = fexp2(s1[r] - M_SHIFT2);
                la += e0; lb2 += e1;
                pw[r]   = f2bf(e0);
                pw[4+r] = f2bf(e1);
            }
            l_r += la + lb2;
            *(bf16x8*)(smem + POFF + cb*8192 + (size_t)(wid*16 + li)*64 + psw) = pw;
        }

        // [5] own LDS reads+writes retired; publish P(t); V(t)+K(t+1) stay in flight
        asm volatile("s_waitcnt lgkmcnt(0)" ::: "memory");
        __builtin_amdgcn_s_barrier();
    }

    // epilogue PV(31): slot 31&1 = 1
    asm volatile("s_waitcnt vmcnt(0)" ::: "memory");
    {
        const char* Pp = smem + POFF + 1*8192;
        const char* Vp = smem + VOFF + 1*32768 + (size_t)(wid*64 + li)*64 + psw;
        bf16x8 bv[4];
        #pragma unroll
        for (int j = 0; j < 4; j++)
            bv[j] = *(const bf16x8*)(Vp + j*1024);
        #pragma unroll
        for (int m = 0; m < 8; m++) {
            bf16x8 pa = *(const bf16x8*)(Pp + (m*16 + li)*64 + psw);
            #pragma unroll
            for (int j = 0; j < 4; j++)
                acc[m*4+j] = __builtin_amdgcn_mfma_f32_16x16x32_bf16(pa, bv[j], acc[m*4+j], 0, 0, 0);
        }
    }

    // reduce l across k-groups; store unnormalized O (bf16) + l
    l_r += __shfl_xor(l_r, 16);
    l_r += __shfl_xor(l_r, 32);

    bf16_t* op = opart + ((size_t)((s*8 + b)*N_DIM) + q0) * D_DIM;
    #pragma unroll
    for (int m = 0; m < 8; m++)
        #pragma unroll
        for (int j = 0; j < 4; j++)
            #pragma unroll
            for (int r = 0; r < 4; r++) {
                int qq = m*16 + g*4 + r;
                int dd = wid*64 + j*16 + li;
                op[(size_t)qq*D_DIM + dd] = f2bf(acc[m*4+j][r]);
            }
    if (lane < 16) {
        stats[(size_t)(s*8 + b)*N_DIM + q0 + wid*16 + lane] = l_r;
    }
}

// ---------------- Kernel 3: merge splits + residual ----------------
__global__ __launch_bounds__(256) void merge3(
    const bf16_t* __restrict__ opart, const float* __restrict__ stats,
    const bf16_t* __restrict__ xnb, float* __restrict__ out)
{
    int row  = (int)((blockIdx.x * blockDim.x + threadIdx.x) >> 6);  // b*2048+n
    int lane = threadIdx.x & 63;
    float l0 = stats[row];
    float l1 = stats[(size_t)16384 + row];
    float rden = 1.f / (l0 + l1);
    size_t base = (size_t)row * D_DIM + lane*8;
    bf16x8 a = *(const bf16x8*)(opart + base);
    bf16x8 c = *(const bf16x8*)(opart + (size_t)16384*D_DIM + base);
    float xv[8];
    if (xnb) {
        bf16x8 xb = *(const bf16x8*)(xnb + base);
        #pragma unroll
        for (int j = 0; j < 8; j++) xv[j] = (float)xb[j];
    } else {
        float4 x0 = *(const float4*)(out + base);
        float4 x1 = *(const float4*)(out + base + 4);
        xv[0]=x0.x; xv[1]=x0.y; xv[2]=x0.z; xv[3]=x0.w;
        xv[4]=x1.x; xv[5]=x1.y; xv[6]=x1.z; xv[7]=x1.w;
    }
    float o[8];
    #pragma unroll
    for (int j = 0; j < 8; j++) o[j] = xv[j] + ((float)a[j] + (float)c[j]) * rden;
    float4 r0 = {o[0], o[1], o[2], o[3]};
    float4 r1 = {o[4], o[5], o[6], o[7]};
    *(float4*)(out + base)     = r0;
    *(float4*)(out + base + 4) = r1;
}

extern "C" void kernel_launch(void* const* d_in, const int* in_sizes, int n_in,
                              void* d_out, int out_size, void* d_ws, size_t ws_size,
                              hipStream_t stream)
{
    const float* x  = (const float*)d_in[0];
    const float* lw = (const float*)d_in[1];
    const float* lb = (const float*)d_in[2];
    const float* qd = (const float*)d_in[3];
    const float* kd = (const float*)d_in[4];
    const float* vd = (const float*)d_in[5];
    float* out = (float*)d_out;

    // ws: qb 16MB | kb 16MB | vT 16MB | opart 32MB | stats 128KB | xnb 16MB (if room)
    const size_t MB = 1024u*1024u;
    char* ws = (char*)d_ws;
    bf16_t* qbuf  = (bf16_t*)(ws);
    bf16_t* kbuf  = (bf16_t*)(ws + 16*MB);
    bf16_t* vTb   = (bf16_t*)(ws + 32*MB);
    bf16_t* opart = (bf16_t*)(ws + 48*MB);
    float*  stats = (float*)(ws + 80*MB);
    bf16_t* xnb   = (ws_size >= 97*MB) ? (bf16_t*)(ws + 81*MB) : nullptr;

    hipFuncSetAttribute((const void*)prep_fused, hipFuncAttributeMaxDynamicSharedMemorySize, 65536);
    hipFuncSetAttribute((const void*)attn8, hipFuncAttributeMaxDynamicSharedMemorySize, SMEM_ATTN);

    prep_fused<<<256, 512, 65536, stream>>>(x, lw, lb, qd, kd, vd, xnb, out, qbuf, kbuf, vTb);
    attn8<<<256, 512, SMEM_ATTN, stream>>>(qbuf, kbuf, vTb, opart, stats);
    merge3<<<4096, 256, 0, stream>>>(opart, stats, xnb, out);
}

// Round 9
// 122.839 us; speedup vs baseline: 1.1348x; 1.1348x over previous
//
#include <hip/hip_runtime.h>
#include <hip/hip_bf16.h>
#include <stdint.h>
#include <math.h>

typedef __bf16 bf16_t;
typedef bf16_t bf16x8 __attribute__((ext_vector_type(8)));
typedef float f32x4 __attribute__((ext_vector_type(4)));

#define B_DIM 8
#define N_DIM 2048
#define D_DIM 512
// (1/sqrt(512)) * log2(e): folded into Q so softmax uses exp2 directly
#define QK_SCALE_L2E 0.063758716f
#define M_SHIFT2 5.7707801635558536f   /* 4 * log2(e); P = exp2(S' - M) = e^(S-4) */

// attn LDS layout (bytes): K ring x3, V dbuf x2  (160 KB exactly)
#define KOFF 0            // 3 x 32768 ([32 k][512 d] bf16, 16B-slot ^ (row&7))
#define VOFF 98304        // 2 x 32768 ([512 d][32 k] bf16, k pre-permuted, slot ^ ((d>>1)&3))
#define SMEM_ATTN 163840

__device__ __forceinline__ bf16_t f2bf(float f) {
    uint32_t u = __builtin_bit_cast(uint32_t, f);
    u += 0x7FFFu + ((u >> 16) & 1u);
    uint16_t h = (uint16_t)(u >> 16);
    return __builtin_bit_cast(bf16_t, h);
}

__device__ __forceinline__ float fexp2(float x) {
    float r;
    asm("v_exp_f32 %0, %1" : "=v"(r) : "v"(x));
    return r;
}

// ---------------- Kernel 1: fused LayerNorm + Q/K prep + permuted V^T ----------------
__global__ __launch_bounds__(512) void prep_fused(
    const float* __restrict__ x, const float* __restrict__ w, const float* __restrict__ bia,
    const float* __restrict__ qd, const float* __restrict__ kd, const float* __restrict__ vd,
    bf16_t* __restrict__ xnb, float* __restrict__ xnf,
    bf16_t* __restrict__ qb, bf16_t* __restrict__ kb, bf16_t* __restrict__ vT)
{
    extern __shared__ char pmem[];
    bf16_t (*vt)[512] = (bf16_t(*)[512])pmem;   // [64 n][512 d], 64 KB

    const int bid = blockIdx.x;
    const int b  = bid >> 5;
    const int n0 = (bid & 31) * 64;
    const int tid  = threadIdx.x;
    const int wid  = tid >> 6;
    const int lane = tid & 63;
    const int d    = lane * 8;

    float wv[8], bv[8], qv[8], kv[8], vv[8];
    {
        float4 t;
        t = *(const float4*)(w  + d);     wv[0]=t.x; wv[1]=t.y; wv[2]=t.z; wv[3]=t.w;
        t = *(const float4*)(w  + d + 4); wv[4]=t.x; wv[5]=t.y; wv[6]=t.z; wv[7]=t.w;
        t = *(const float4*)(bia+ d);     bv[0]=t.x; bv[1]=t.y; bv[2]=t.z; bv[3]=t.w;
        t = *(const float4*)(bia+ d + 4); bv[4]=t.x; bv[5]=t.y; bv[6]=t.z; bv[7]=t.w;
        t = *(const float4*)(qd + d);     qv[0]=t.x; qv[1]=t.y; qv[2]=t.z; qv[3]=t.w;
        t = *(const float4*)(qd + d + 4); qv[4]=t.x; qv[5]=t.y; qv[6]=t.z; qv[7]=t.w;
        t = *(const float4*)(kd + d);     kv[0]=t.x; kv[1]=t.y; kv[2]=t.z; kv[3]=t.w;
        t = *(const float4*)(kd + d + 4); kv[4]=t.x; kv[5]=t.y; kv[6]=t.z; kv[7]=t.w;
        t = *(const float4*)(vd + d);     vv[0]=t.x; vv[1]=t.y; vv[2]=t.z; vv[3]=t.w;
        t = *(const float4*)(vd + d + 4); vv[4]=t.x; vv[5]=t.y; vv[6]=t.z; vv[7]=t.w;
    }

    for (int r = 0; r < 8; r++) {
        int nl = wid*8 + r;
        size_t row  = (size_t)b*N_DIM + n0 + nl;
        size_t base = row*D_DIM + d;
        float xv[8];
        {
            float4 a0 = *(const float4*)(x + base);
            float4 a1 = *(const float4*)(x + base + 4);
            xv[0]=a0.x; xv[1]=a0.y; xv[2]=a0.z; xv[3]=a0.w;
            xv[4]=a1.x; xv[5]=a1.y; xv[6]=a1.z; xv[7]=a1.w;
        }
        float s = 0.f, s2 = 0.f;
        #pragma unroll
        for (int j = 0; j < 8; j++) { s += xv[j]; s2 += xv[j]*xv[j]; }
        #pragma unroll
        for (int m = 1; m < 64; m <<= 1) {
            s  += __shfl_xor(s,  m);
            s2 += __shfl_xor(s2, m);
        }
        float mu   = s  * (1.f/512.f);
        float var  = s2 * (1.f/512.f) - mu*mu;
        float rstd = rsqrtf(var + 1e-5f);

        float xo[8];
        bf16x8 qo, ko, xb, vb;
        #pragma unroll
        for (int j = 0; j < 8; j++) {
            float v = (xv[j] - mu) * rstd * wv[j] + bv[j];
            xo[j] = v;
            xb[j] = f2bf(v);
            qo[j] = f2bf(v * qv[j] * QK_SCALE_L2E);
            ko[j] = f2bf(v * kv[j]);
            vb[j] = f2bf(v * vv[j]);
        }
        if (xnb) {
            *(bf16x8*)(xnb + base) = xb;
        } else {
            float4 o0 = {xo[0],xo[1],xo[2],xo[3]};
            float4 o1 = {xo[4],xo[5],xo[6],xo[7]};
            *(float4*)(xnf + base)     = o0;
            *(float4*)(xnf + base + 4) = o1;
        }
        *(bf16x8*)(qb + base) = qo;
        *(bf16x8*)(kb + base) = ko;
        *(bf16x8*)(&vt[nl][d]) = vb;
    }
    __syncthreads();

    // vT: slot sp holds logical g = sp ^ ((d>>1)&3): k = {4g..4g+3, 16+4g..16+4g+3}
    {
        const int dd = tid;
        const int salt = (dd >> 1) & 3;
        bf16_t* vrow = vT + ((size_t)(b*D_DIM + dd))*N_DIM + n0;
        #pragma unroll
        for (int kb2 = 0; kb2 < 2; kb2++) {
            #pragma unroll
            for (int sp = 0; sp < 4; sp++) {
                int gg = sp ^ salt;
                bf16x8 o;
                #pragma unroll
                for (int e = 0; e < 4; e++) o[e]   = vt[kb2*32 + 4*gg + e][dd];
                #pragma unroll
                for (int e = 0; e < 4; e++) o[4+e] = vt[kb2*32 + 16 + 4*gg + e][dd];
                *(bf16x8*)(vrow + kb2*32 + sp*8) = o;
            }
        }
    }
}

// ---------------- Kernel 2: flash attention (split-KV, swapped QK^T, P-in-reg) ----------------
// grid 256: XCD-grouped (batch,split) x 16 qtiles. 512 thr = 8 waves.
// attn6 structure + K ring-3 + counted vmcnt: iter t issues V(t+1), K(t+2);
// [E] waits vmcnt(4) (retires K(t+1),V(t+1); K(t+2) stays in flight across the
// barrier). K arrival window = 2 iterations; pipeline never drains in the loop.
__global__ __launch_bounds__(512, 2) void attn9(
    const bf16_t* __restrict__ qb, const bf16_t* __restrict__ kb,
    const bf16_t* __restrict__ vT, bf16_t* __restrict__ opart, float* __restrict__ stats)
{
    extern __shared__ char smem[];

    const int bid = blockIdx.x;
    const int xcd = bid & 7, jj = bid >> 3;
    const int grp = xcd + 8*(jj >> 4);   // (b,s) group -> one XCD
    const int qt  = jj & 15;
    const int b   = grp >> 1;
    const int s   = grp & 1;
    const int q0  = qt * 128;
    const int n0base = s * 1024;

    const int tid  = threadIdx.x;
    const int wid  = tid >> 6;
    const int lane = tid & 63;
    const int g    = lane >> 4;
    const int li   = lane & 15;

    const bf16_t* kb_b = kb + (size_t)b * N_DIM * D_DIM;
    const bf16_t* vT_b = vT + (size_t)b * D_DIM * N_DIM;

    // Q fragments (loop-invariant): rows q0 + wid*16 + li over all 512 d
    bf16x8 qf[16];
    {
        const bf16_t* qp = qb + ((size_t)(b*N_DIM + q0 + wid*16 + li)) * D_DIM + g*8;
        #pragma unroll
        for (int ks = 0; ks < 16; ks++)
            qf[ks] = *(const bf16x8*)(qp + ks*32);
    }

    f32x4 acc[32];
    const f32x4 zf = {0.f, 0.f, 0.f, 0.f};
    #pragma unroll
    for (int j = 0; j < 32; j++) acc[j] = zf;

    float l_r = 0.f;

    const int Lk = (lane ^ wid) * 8;
    auto stageK = [&](int slot, int t) {
        const int kstart = n0base + t*32;
        char* kdst = smem + KOFF + slot*32768;
        #pragma unroll
        for (int v = 0; v < 4; v++) {
            int row = v*8 + wid;
            const bf16_t* src = kb_b + (size_t)(kstart + row)*D_DIM + Lk;
            __builtin_amdgcn_global_load_lds((const void*)src, (void*)(kdst + row*1024), 16, 0, 0);
        }
    };
    auto stageV = [&](int buf, int t) {
        const int kstart = n0base + t*32;
        char* vdst = smem + VOFF + buf*32768 + wid*4096;
        const int drow = wid*64 + (lane >> 2);
        const bf16_t* src0 = vT_b + (size_t)drow*N_DIM + kstart + (lane & 3)*8;
        #pragma unroll
        for (int v = 0; v < 4; v++) {
            __builtin_amdgcn_global_load_lds((const void*)(src0 + (size_t)(v*16)*N_DIM),
                                             (void*)(vdst + v*1024), 16, 0, 0);
        }
    };

    // prologue: issue K(0), V(0), K(1); vmcnt(4) retires K(0),V(0); K(1) in flight
    stageK(0, 0);
    stageV(0, 0);
    stageK(1, 1);
    asm volatile("s_waitcnt vmcnt(4)" ::: "memory");
    __builtin_amdgcn_s_barrier();

    const int sw  = li & 7;                      // K-read salt
    const int vsw = (g ^ ((li >> 1) & 3)) << 4;  // V-read slot (lane-constant)

    int kc = 0;                                  // t % 3 (K ring read slot)

    #pragma unroll 1
    for (int t = 0; t < 32; ++t) {
        const int vbuf = t & 1;
        const int ks2  = (kc + 2 >= 3) ? (kc + 2 - 3) : (kc + 2);  // (t+2)%3

        // [A] issue V(t+1) then K(t+2); both fly across the body (and K across the barrier)
        if (t < 31) stageV(vbuf ^ 1, t + 1);
        if (t < 30) stageK(ks2, t + 2);
        __builtin_amdgcn_sched_barrier(0);

        // [B] swapped QK^T: S^T[32 k][16 q]; lane: q=li, k = 4g+r (s0) / 16+4g+r (s1)
        const char* kr0 = smem + KOFF + kc*32768 + li*1024;
        const char* kr1 = kr0 + 16*1024;
        f32x4 s0 = zf, s1 = zf;
        __builtin_amdgcn_s_setprio(1);
        #pragma unroll
        for (int ks = 0; ks < 16; ks++) {
            int phys = (((ks << 2) + g) ^ sw) << 4;
            bf16x8 k0 = *(const bf16x8*)(kr0 + phys);
            bf16x8 k1 = *(const bf16x8*)(kr1 + phys);
            s0 = __builtin_amdgcn_mfma_f32_16x16x32_bf16(k0, qf[ks], s0, 0, 0, 0);
            s1 = __builtin_amdgcn_mfma_f32_16x16x32_bf16(k1, qf[ks], s1, 0, 0, 0);
        }
        __builtin_amdgcn_s_setprio(0);

        // [C] static-shift softmax, lane-local; P packs directly into the PV A-frag
        float p0[4], p1[4];
        #pragma unroll
        for (int r = 0; r < 4; r++) {
            p0[r] = fexp2(s0[r] - M_SHIFT2);
            p1[r] = fexp2(s1[r] - M_SHIFT2);
        }
        l_r += ((p0[0]+p0[1]) + (p0[2]+p0[3])) + ((p1[0]+p1[1]) + (p1[2]+p1[3]));
        bf16x8 af;
        af[0]=f2bf(p0[0]); af[1]=f2bf(p0[1]); af[2]=f2bf(p0[2]); af[3]=f2bf(p0[3]);
        af[4]=f2bf(p1[0]); af[5]=f2bf(p1[1]); af[6]=f2bf(p1[2]); af[7]=f2bf(p1[3]);

        // [D] PV: O[16q][512d] += P * V; B-frags from V-LDS (k pre-permuted to match af)
        const char* Vb = smem + VOFF + vbuf*32768 + li*64 + vsw;
        __builtin_amdgcn_s_setprio(1);
        #pragma unroll
        for (int j = 0; j < 32; j++) {
            bf16x8 bv = *(const bf16x8*)(Vb + j*1024);
            acc[j] = __builtin_amdgcn_mfma_f32_16x16x32_bf16(af, bv, acc[j], 0, 0, 0);
        }
        __builtin_amdgcn_s_setprio(0);

        // [E] counted publish: retire K(t+1)+V(t+1) (K(t+2) stays in flight);
        //     tail t=30 drains (no K(33) was issued). Own LDS reads retired (lgkm).
        if (t < 31) {
            if (t < 30) {
                asm volatile("s_waitcnt vmcnt(4) lgkmcnt(0)" ::: "memory");
            } else {
                asm volatile("s_waitcnt vmcnt(0) lgkmcnt(0)" ::: "memory");
            }
            __builtin_amdgcn_s_barrier();
        }

        kc = (kc + 1 >= 3) ? 0 : kc + 1;
    }

    // ---- epilogue: reduce l across k-groups, store unnormalized O (bf16) + l ----
    l_r += __shfl_xor(l_r, 16);
    l_r += __shfl_xor(l_r, 32);

    bf16_t* op = opart + ((size_t)((s*8 + b)*N_DIM) + q0 + wid*16) * D_DIM;
    #pragma unroll
    for (int j = 0; j < 32; j++)
        #pragma unroll
        for (int r = 0; r < 4; r++)
            op[(size_t)(4*g + r)*D_DIM + j*16 + li] = f2bf(acc[j][r]);

    if (lane < 16) {
        stats[(size_t)(s*8 + b)*N_DIM + q0 + wid*16 + lane] = l_r;
    }
}

// ---------------- Kernel 3: merge splits + residual ----------------
__global__ __launch_bounds__(256) void merge3(
    const bf16_t* __restrict__ opart, const float* __restrict__ stats,
    const bf16_t* __restrict__ xnb, float* __restrict__ out)
{
    int row  = (int)((blockIdx.x * blockDim.x + threadIdx.x) >> 6);  // b*2048+n
    int lane = threadIdx.x & 63;
    float l0 = stats[row];
    float l1 = stats[(size_t)16384 + row];
    float rden = 1.f / (l0 + l1);
    size_t base = (size_t)row * D_DIM + lane*8;
    bf16x8 a = *(const bf16x8*)(opart + base);
    bf16x8 c = *(const bf16x8*)(opart + (size_t)16384*D_DIM + base);
    float xv[8];
    if (xnb) {
        bf16x8 xb = *(const bf16x8*)(xnb + base);
        #pragma unroll
        for (int j = 0; j < 8; j++) xv[j] = (float)xb[j];
    } else {
        float4 x0 = *(const float4*)(out + base);
        float4 x1 = *(const float4*)(out + base + 4);
        xv[0]=x0.x; xv[1]=x0.y; xv[2]=x0.z; xv[3]=x0.w;
        xv[4]=x1.x; xv[5]=x1.y; xv[6]=x1.z; xv[7]=x1.w;
    }
    float o[8];
    #pragma unroll
    for (int j = 0; j < 8; j++) o[j] = xv[j] + ((float)a[j] + (float)c[j]) * rden;
    float4 r0 = {o[0], o[1], o[2], o[3]};
    float4 r1 = {o[4], o[5], o[6], o[7]};
    *(float4*)(out + base)     = r0;
    *(float4*)(out + base + 4) = r1;
}

extern "C" void kernel_launch(void* const* d_in, const int* in_sizes, int n_in,
                              void* d_out, int out_size, void* d_ws, size_t ws_size,
                              hipStream_t stream)
{
    const float* x  = (const float*)d_in[0];
    const float* lw = (const float*)d_in[1];
    const float* lb = (const float*)d_in[2];
    const float* qd = (const float*)d_in[3];
    const float* kd = (const float*)d_in[4];
    const float* vd = (const float*)d_in[5];
    float* out = (float*)d_out;

    // ws: qb 16MB | kb 16MB | vT 16MB | opart 32MB | stats 128KB | xnb 16MB (if room)
    const size_t MB = 1024u*1024u;
    char* ws = (char*)d_ws;
    bf16_t* qbuf  = (bf16_t*)(ws);
    bf16_t* kbuf  = (bf16_t*)(ws + 16*MB);
    bf16_t* vTb   = (bf16_t*)(ws + 32*MB);
    bf16_t* opart = (bf16_t*)(ws + 48*MB);
    float*  stats = (float*)(ws + 80*MB);
    bf16_t* xnb   = (ws_size >= 97*MB) ? (bf16_t*)(ws + 81*MB) : nullptr;

    hipFuncSetAttribute((const void*)prep_fused, hipFuncAttributeMaxDynamicSharedMemorySize, 65536);
    hipFuncSetAttribute((const void*)attn9, hipFuncAttributeMaxDynamicSharedMemorySize, SMEM_ATTN);

    prep_fused<<<256, 512, 65536, stream>>>(x, lw, lb, qd, kd, vd, xnb, out, qbuf, kbuf, vTb);
    attn9<<<256, 512, SMEM_ATTN, stream>>>(qbuf, kbuf, vTb, opart, stats);
    merge3<<<4096, 256, 0, stream>>>(opart, stats, xnb, out);
}